// Round 10
// baseline (134.152 us; speedup 1.0000x reference)
//
#include <hip/hip_runtime.h>

#define BIGF 1e9f
#define TT 512
#define DD 256
#define NB 64
#define DROWS 1088    // diag rows per batch (1023 used + prefetch overrun pad)
#define SAK 72        // LDS row stride in bf16 (64 data + 8 pad)

typedef float floatx16 __attribute__((ext_vector_type(16)));
typedef __bf16 bf16x8 __attribute__((ext_vector_type(8)));

// ---------- DPP wave shifts: lane i <- lane i-1 (shr) / lane i+1 (shl); invalid lanes get `oldv`
__device__ __forceinline__ float dpp_wave_shr1(float x, float oldv) {
  int r = __builtin_amdgcn_update_dpp(__builtin_bit_cast(int, oldv),
                                      __builtin_bit_cast(int, x),
                                      0x138, 0xF, 0xF, false);  // WAVE_SHR1
  return __builtin_bit_cast(float, r);
}
__device__ __forceinline__ float dpp_wave_shl1(float x, float oldv) {
  int r = __builtin_amdgcn_update_dpp(__builtin_bit_cast(int, oldv),
                                      __builtin_bit_cast(int, x),
                                      0x130, 0xF, 0xF, false);  // WAVE_SHL1
  return __builtin_bit_cast(float, r);
}

__device__ __forceinline__ bf16x8 cvt8(const float4 a, const float4 b) {
  bf16x8 v;
  v[0] = (__bf16)a.x; v[1] = (__bf16)a.y; v[2] = (__bf16)a.z; v[3] = (__bf16)a.w;
  v[4] = (__bf16)b.x; v[5] = (__bf16)b.y; v[6] = (__bf16)b.z; v[7] = (__bf16)b.w;
  return v;
}
__device__ __forceinline__ float sq4(const float4 a) {
  return a.x * a.x + a.y * a.y + a.z * a.z + a.w * a.w;
}

// ---------- Kernel B: banded cost via bf16 MFMA + fused norms, written in diag layout ----------
// 64x64 (i,j) tile per block; 4 waves in 2x2; each wave one 32x32 MFMA accumulator.
// Block n -> batch b=n%64 (XCD b%8): per-batch x1/x2 stay L2-resident.
// K-chunk 64, software-pipelined: chunk k+1's global loads issue right after barrier-2
// of chunk k; first consumer (LDS write) is a full iteration later, so HBM latency is
// exposed only once (prologue) instead of 8x. m==0 blocks paint corner-invalid diag
// cells with BIG (disjoint from all valid-cell writes; poison 0xAA = -3e-13 must not leak).
__global__ __launch_bounds__(256) void cost_kernel(const float* __restrict__ x1,
                                                   const float* __restrict__ x2,
                                                   float* __restrict__ diag) {
  const int n = blockIdx.x;
  const int b = n & 63;       // batch; b%8 == n%8 -> XCD
  const int m = n >> 6;       // 0..23
  const int it = m & 7;       // i-tile
  const int jt = m >> 3;      // j-tile 0..2
  const int i0 = it * 64;
  const int j0 = i0 - 50 + jt * 64;

  __shared__ __align__(16) __bf16 sA[64 * SAK];
  __shared__ __align__(16) __bf16 sB[64 * SAK];
  __shared__ float rA[64];  // 1/max(||x1_i||, eps) per tile row
  __shared__ float rB[64];

  const int t = threadIdx.x;
  const int lane = t & 63;
  const int w = t >> 6;       // wave 0..3
  const int wi = w >> 1;      // i-subtile (0/1)
  const int wj = w & 1;       // j-subtile (0/1)
  const int ln = lane & 31;
  const int kh = lane >> 5;   // k-half (0/1)

  float* db = diag + (size_t)b * (DROWS * 64);

  // corner paint (one block per batch; overlapped with the other 1472 blocks' compute)
  if (m == 0) {
    for (int r = w; r < 180; r += 4) {
      const int d = (r < 64) ? r : r + 908;  // [0,64) U [972,1088)
      const int p = d & 1;
      const int i = (d >> 1) + lane + p - 25;
      const int j = d - i;
      const int k = 2 * lane + p;
      if (k > 100 || (unsigned)i >= TT || (unsigned)j >= TT)
        db[(size_t)d * 64 + lane] = BIGF;
    }
  }

  // staging mapping: thread t covers row (t>>2), 16 consecutive floats at (t&3)*16
  const int sr = t >> 2;
  const int sq = t & 3;
  const float* x1b = x1 + (size_t)b * (TT * DD);
  const float* x2b = x2 + (size_t)b * (TT * DD);
  int gj = j0 + sr;
  gj = gj < 0 ? 0 : (gj > TT - 1 ? TT - 1 : gj);
  const float* pAg = x1b + (size_t)(i0 + sr) * DD + sq * 16;
  const float* pBg = x2b + (size_t)gj * DD + sq * 16;
  __bf16* dA = sA + sr * SAK + sq * 16;
  __bf16* dB = sB + sr * SAK + sq * 16;

  const __bf16* fAp = sA + (wi * 32 + ln) * SAK + kh * 8;
  const __bf16* fBp = sB + (wj * 32 + ln) * SAK + kh * 8;

  floatx16 acc = {};
  float pa = 0.f, pb = 0.f;  // sum-of-squares partials (fp32, from original data)

  // prologue: loads for chunk 0
  float4 a0 = *(const float4*)(pAg + 0);
  float4 a1 = *(const float4*)(pAg + 4);
  float4 a2 = *(const float4*)(pAg + 8);
  float4 a3 = *(const float4*)(pAg + 12);
  float4 b0 = *(const float4*)(pBg + 0);
  float4 b1 = *(const float4*)(pBg + 4);
  float4 b2 = *(const float4*)(pBg + 8);
  float4 b3 = *(const float4*)(pBg + 12);

#pragma unroll
  for (int kc = 0; kc < DD; kc += 64) {
    __syncthreads();  // LDS consumers of previous chunk done
    *(bf16x8*)dA = cvt8(a0, a1);
    *(bf16x8*)(dA + 8) = cvt8(a2, a3);
    *(bf16x8*)dB = cvt8(b0, b1);
    *(bf16x8*)(dB + 8) = cvt8(b2, b3);
    pa += sq4(a0) + sq4(a1) + sq4(a2) + sq4(a3);
    pb += sq4(b0) + sq4(b1) + sq4(b2) + sq4(b3);
    __syncthreads();  // LDS chunk visible
    if (kc + 64 < DD) {  // prefetch next chunk; first consumer is next iter's LDS write
      a0 = *(const float4*)(pAg + kc + 64);
      a1 = *(const float4*)(pAg + kc + 68);
      a2 = *(const float4*)(pAg + kc + 72);
      a3 = *(const float4*)(pAg + kc + 76);
      b0 = *(const float4*)(pBg + kc + 64);
      b1 = *(const float4*)(pBg + kc + 68);
      b2 = *(const float4*)(pBg + kc + 72);
      b3 = *(const float4*)(pBg + kc + 76);
    }
#pragma unroll
    for (int s = 0; s < 4; ++s) {
      const bf16x8 fa = *(const bf16x8*)(fAp + s * 16);
      const bf16x8 fb = *(const bf16x8*)(fBp + s * 16);
      acc = __builtin_amdgcn_mfma_f32_32x32x16_bf16(fa, fb, acc, 0, 0, 0);
    }
  }

  // reduce sumsq across the 4 staging threads of each row (lanes t^1, t^2 share sr)
  pa += __shfl_xor(pa, 1, 64); pa += __shfl_xor(pa, 2, 64);
  pb += __shfl_xor(pb, 1, 64); pb += __shfl_xor(pb, 2, 64);
  if (sq == 0) {
    rA[sr] = 1.0f / fmaxf(sqrtf(pa), 1e-8f);
    rB[sr] = 1.0f / fmaxf(sqrtf(pb), 1e-8f);
  }
  __syncthreads();

  // epilogue: C layout col=lane&31 (j), row=(reg&3)+8*(reg>>2)+4*(lane>>5) (i)
  // write directly to diag[b][d=i+j][l=(i-j+50)>>1]
  const int j = j0 + wj * 32 + ln;
  const float r2 = rB[wj * 32 + ln];
#pragma unroll
  for (int reg = 0; reg < 16; ++reg) {
    const int ri = wi * 32 + (reg & 3) + 8 * (reg >> 2) + 4 * kh;
    const int i = i0 + ri;
    const int k = i - j + 50;
    if ((unsigned)j < TT && (unsigned)k <= 100) {
      const float v = 1.0f - acc[reg] * rA[ri] * r2;
      db[(size_t)(i + j) * 64 + (k >> 1)] = v;
    }
  }
}

// ---------- Kernel C: anti-diagonal DP, one wave per batch, coalesced diag reads ----------
// Band offset k = i-j+50; lane l holds cell k = 2l+p (p = d&1).
// new[k] = c + min(prev1[k-1], prev1[k+1], prev2[k])
//   p=1 (odd d): k-1 -> same lane, k+1 -> wave_shl1;  p=0: k-1 -> wave_shr1, k+1 -> same lane.
// min(prev1,prev2) computes in parallel with the DPP shift -> serial path dpp->min->add.
// Lanes l>=51 (and l==50 on odd d) masked arithmetically off the critical chain;
// corner diagonals were BIG-painted by cost_kernel's m==0 blocks.
__global__ __launch_bounds__(64) void dtw_dp_kernel(const float* __restrict__ diag,
                                                    float* __restrict__ out) {
  const int b = blockIdx.x;
  const int l = threadIdx.x;
  const bool inv_odd = (l >= 50);   // k=2l+1 > 100
  const bool inv_even = (l >= 51);  // k=2l   > 100
  const float* base = diag + (size_t)b * (DROWS * 64);
  const float* pO = base + 64 + l;   // d = 1
  const float* pE = base + 128 + l;  // d = 2
  float cr[32];
#pragma unroll
  for (int t = 0; t < 16; ++t) {
    cr[2 * t] = *pO; pO += 128;
    cr[2 * t + 1] = *pE; pE += 128;
  }
  float prev2 = BIGF;
  const float c00 = base[25];          // cost(0,0) lives at d=0, lane 25
  float prev1 = (l == 25) ? c00 : BIGF;
  float ans = BIGF;
  for (int it = 0; it < 32; ++it) {
#pragma unroll
    for (int u = 0; u < 16; ++u) {
      // odd diagonal
      const float c1 = inv_odd ? BIGF : cr[2 * u];
      cr[2 * u] = *pO; pO += 128;  // prefetch 32 diagonals ahead (stays within DROWS pad)
      const float m12 = fminf(prev1, prev2);     // off-chain, overlaps DPP
      const float sh = dpp_wave_shl1(prev1, BIGF);
      const float m3 = fminf(sh, m12);
      prev2 = prev1;
      prev1 = c1 + m3;
      // even diagonal
      const float c2 = inv_even ? BIGF : cr[2 * u + 1];
      cr[2 * u + 1] = *pE; pE += 128;
      const float m12b = fminf(prev1, prev2);
      const float sh2 = dpp_wave_shr1(prev1, BIGF);
      const float m32 = fminf(sh2, m12b);
      prev2 = prev1;
      prev1 = c2 + m32;
      if (u == 14 && it == 31) ans = prev1;  // d = 1022 -> cell (511,511) at lane 25
    }
  }
  if (l == 25) out[b] = ans;
}

extern "C" void kernel_launch(void* const* d_in, const int* in_sizes, int n_in,
                              void* d_out, int out_size, void* d_ws, size_t ws_size,
                              hipStream_t stream) {
  const float* x1 = (const float*)d_in[0];
  const float* x2 = (const float*)d_in[1];
  float* out = (float*)d_out;
  float* diag = (float*)d_ws;  // 64*1088*64 floats = 17.8 MB

  cost_kernel<<<NB * 24, 256, 0, stream>>>(x1, x2, diag);
  dtw_dp_kernel<<<NB, 64, 0, stream>>>(diag, out);
}

// Round 11
// 128.973 us; speedup vs baseline: 1.0401x; 1.0401x over previous
//
#include <hip/hip_runtime.h>

#define BIGF 1e9f
#define TT 512
#define DD 256
#define NB 64
#define DROWS 1088    // diag rows per batch (1023 used + prefetch overrun pad)
#define SAK 40        // LDS row stride in bf16 (32 data + 8 pad)

typedef float floatx16 __attribute__((ext_vector_type(16)));
typedef __bf16 bf16x8 __attribute__((ext_vector_type(8)));

// ---------- DPP wave shifts: lane i <- lane i-1 (shr) / lane i+1 (shl); invalid lanes get `oldv`
__device__ __forceinline__ float dpp_wave_shr1(float x, float oldv) {
  int r = __builtin_amdgcn_update_dpp(__builtin_bit_cast(int, oldv),
                                      __builtin_bit_cast(int, x),
                                      0x138, 0xF, 0xF, false);  // WAVE_SHR1
  return __builtin_bit_cast(float, r);
}
__device__ __forceinline__ float dpp_wave_shl1(float x, float oldv) {
  int r = __builtin_amdgcn_update_dpp(__builtin_bit_cast(int, oldv),
                                      __builtin_bit_cast(int, x),
                                      0x130, 0xF, 0xF, false);  // WAVE_SHL1
  return __builtin_bit_cast(float, r);
}

__device__ __forceinline__ bf16x8 cvt8(const float4 a, const float4 b) {
  bf16x8 v;
  v[0] = (__bf16)a.x; v[1] = (__bf16)a.y; v[2] = (__bf16)a.z; v[3] = (__bf16)a.w;
  v[4] = (__bf16)b.x; v[5] = (__bf16)b.y; v[6] = (__bf16)b.z; v[7] = (__bf16)b.w;
  return v;
}
__device__ __forceinline__ float sq4(const float4 a) {
  return a.x * a.x + a.y * a.y + a.z * a.z + a.w * a.w;
}

// ---------- Kernel B: banded cost via bf16 MFMA + fused norms, written in diag layout ----------
// 64x64 (i,j) tile per block; 4 waves in 2x2; each wave one 32x32 MFMA accumulator.
// Block n -> batch b=n%64 (XCD b%8): per-batch x1/x2 stay L2-resident.
// K-loop starting chunk rotated by (m&7): co-resident blocks on a CU sit in DIFFERENT
// k-phases, so one block's HBM-wait overlaps another's LDS/MFMA phase (breaks the
// lockstep convoy; fp32 accumulation order is correctness-neutral).
// m==0 blocks paint corner-invalid diag cells with BIG (poison 0xAA = -3e-13 must not
// leak into the DP); painted cells are disjoint from all valid-cell writes.
__global__ __launch_bounds__(256) void cost_kernel(const float* __restrict__ x1,
                                                   const float* __restrict__ x2,
                                                   float* __restrict__ diag) {
  const int n = blockIdx.x;
  const int b = n & 63;       // batch; b%8 == n%8 -> XCD
  const int m = n >> 6;       // 0..23
  const int it = m & 7;       // i-tile
  const int jt = m >> 3;      // j-tile 0..2
  const int i0 = it * 64;
  const int j0 = i0 - 50 + jt * 64;
  const int ph = m & 7;       // k-phase rotation

  __shared__ __align__(16) __bf16 sA[64 * SAK];
  __shared__ __align__(16) __bf16 sB[64 * SAK];
  __shared__ float rA[64];  // 1/max(||x1_i||, eps) per tile row
  __shared__ float rB[64];

  const int t = threadIdx.x;
  const int lane = t & 63;
  const int w = t >> 6;       // wave 0..3
  const int wi = w >> 1;      // i-subtile (0/1)
  const int wj = w & 1;       // j-subtile (0/1)
  const int ln = lane & 31;
  const int kh = lane >> 5;   // k-half (0/1)

  float* db = diag + (size_t)b * (DROWS * 64);

  // corner paint (one block per batch; overlapped with the other 1472 blocks' compute)
  if (m == 0) {
    for (int r = w; r < 180; r += 4) {
      const int d = (r < 64) ? r : r + 908;  // [0,64) U [972,1088)
      const int p = d & 1;
      const int i = (d >> 1) + lane + p - 25;
      const int j = d - i;
      const int k = 2 * lane + p;
      if (k > 100 || (unsigned)i >= TT || (unsigned)j >= TT)
        db[(size_t)d * 64 + lane] = BIGF;
    }
  }

  // staging mapping: thread t covers row (t>>2), 8 floats at quarter (t&3)
  const int sr = t >> 2;
  const int sq = t & 3;
  const float* x1b = x1 + (size_t)b * (TT * DD);
  const float* x2b = x2 + (size_t)b * (TT * DD);
  int gj = j0 + sr;
  gj = gj < 0 ? 0 : (gj > TT - 1 ? TT - 1 : gj);
  const float* pAg = x1b + (size_t)(i0 + sr) * DD + sq * 8;
  const float* pBg = x2b + (size_t)gj * DD + sq * 8;
  __bf16* dA = sA + sr * SAK + sq * 8;
  __bf16* dB = sB + sr * SAK + sq * 8;

  const __bf16* fAp = sA + (wi * 32 + ln) * SAK + kh * 8;
  const __bf16* fBp = sB + (wj * 32 + ln) * SAK + kh * 8;

  floatx16 acc = {};
  float pa = 0.f, pb = 0.f;  // sum-of-squares partials (fp32, from original data)

  for (int r = 0; r < 8; ++r) {
    const int kc = ((r + ph) & 7) * 32;  // rotated chunk order
    const float4 a0 = *(const float4*)(pAg + kc);
    const float4 a1 = *(const float4*)(pAg + kc + 4);
    const float4 b0 = *(const float4*)(pBg + kc);
    const float4 b1 = *(const float4*)(pBg + kc + 4);
    pa += sq4(a0) + sq4(a1);
    pb += sq4(b0) + sq4(b1);
    __syncthreads();
    *(bf16x8*)dA = cvt8(a0, a1);
    *(bf16x8*)dB = cvt8(b0, b1);
    __syncthreads();
    const bf16x8 fa0 = *(const bf16x8*)fAp;
    const bf16x8 fb0 = *(const bf16x8*)fBp;
    const bf16x8 fa1 = *(const bf16x8*)(fAp + 16);
    const bf16x8 fb1 = *(const bf16x8*)(fBp + 16);
    acc = __builtin_amdgcn_mfma_f32_32x32x16_bf16(fa0, fb0, acc, 0, 0, 0);
    acc = __builtin_amdgcn_mfma_f32_32x32x16_bf16(fa1, fb1, acc, 0, 0, 0);
  }

  // reduce sumsq across the 4 staging threads of each row (lanes t^1, t^2 share sr)
  pa += __shfl_xor(pa, 1, 64); pa += __shfl_xor(pa, 2, 64);
  pb += __shfl_xor(pb, 1, 64); pb += __shfl_xor(pb, 2, 64);
  if (sq == 0) {
    rA[sr] = 1.0f / fmaxf(sqrtf(pa), 1e-8f);
    rB[sr] = 1.0f / fmaxf(sqrtf(pb), 1e-8f);
  }
  __syncthreads();

  // epilogue: C layout col=lane&31 (j), row=(reg&3)+8*(reg>>2)+4*(lane>>5) (i)
  // write directly to diag[b][d=i+j][l=(i-j+50)>>1]
  const int j = j0 + wj * 32 + ln;
  const float r2 = rB[wj * 32 + ln];
#pragma unroll
  for (int reg = 0; reg < 16; ++reg) {
    const int ri = wi * 32 + (reg & 3) + 8 * (reg >> 2) + 4 * kh;
    const int i = i0 + ri;
    const int k = i - j + 50;
    if ((unsigned)j < TT && (unsigned)k <= 100) {
      const float v = 1.0f - acc[reg] * rA[ri] * r2;
      db[(size_t)(i + j) * 64 + (k >> 1)] = v;
    }
  }
}

// ---------- Kernel C: anti-diagonal DP, one wave per batch, coalesced diag reads ----------
// Band offset k = i-j+50; lane l holds cell k = 2l+p (p = d&1).
// new[k] = c + min(prev1[k-1], prev1[k+1], prev2[k])
//   p=1 (odd d): k-1 -> same lane, k+1 -> wave_shl1;  p=0: k-1 -> wave_shr1, k+1 -> same lane.
// min(prev1,prev2) computes in parallel with the DPP shift -> serial path dpp->min->add.
// Lanes l>=51 (and l==50 on odd d) masked arithmetically off the critical chain;
// corner diagonals were BIG-painted by cost_kernel's m==0 blocks.
__global__ __launch_bounds__(64) void dtw_dp_kernel(const float* __restrict__ diag,
                                                    float* __restrict__ out) {
  const int b = blockIdx.x;
  const int l = threadIdx.x;
  const bool inv_odd = (l >= 50);   // k=2l+1 > 100
  const bool inv_even = (l >= 51);  // k=2l   > 100
  const float* base = diag + (size_t)b * (DROWS * 64);
  const float* pO = base + 64 + l;   // d = 1
  const float* pE = base + 128 + l;  // d = 2
  float cr[32];
#pragma unroll
  for (int t = 0; t < 16; ++t) {
    cr[2 * t] = *pO; pO += 128;
    cr[2 * t + 1] = *pE; pE += 128;
  }
  float prev2 = BIGF;
  const float c00 = base[25];          // cost(0,0) lives at d=0, lane 25
  float prev1 = (l == 25) ? c00 : BIGF;
  float ans = BIGF;
  for (int it = 0; it < 32; ++it) {
#pragma unroll
    for (int u = 0; u < 16; ++u) {
      // odd diagonal
      const float c1 = inv_odd ? BIGF : cr[2 * u];
      cr[2 * u] = *pO; pO += 128;  // prefetch 32 diagonals ahead (stays within DROWS pad)
      const float m12 = fminf(prev1, prev2);     // off-chain, overlaps DPP
      const float sh = dpp_wave_shl1(prev1, BIGF);
      const float m3 = fminf(sh, m12);
      prev2 = prev1;
      prev1 = c1 + m3;
      // even diagonal
      const float c2 = inv_even ? BIGF : cr[2 * u + 1];
      cr[2 * u + 1] = *pE; pE += 128;
      const float m12b = fminf(prev1, prev2);
      const float sh2 = dpp_wave_shr1(prev1, BIGF);
      const float m32 = fminf(sh2, m12b);
      prev2 = prev1;
      prev1 = c2 + m32;
      if (u == 14 && it == 31) ans = prev1;  // d = 1022 -> cell (511,511) at lane 25
    }
  }
  if (l == 25) out[b] = ans;
}

extern "C" void kernel_launch(void* const* d_in, const int* in_sizes, int n_in,
                              void* d_out, int out_size, void* d_ws, size_t ws_size,
                              hipStream_t stream) {
  const float* x1 = (const float*)d_in[0];
  const float* x2 = (const float*)d_in[1];
  float* out = (float*)d_out;
  float* diag = (float*)d_ws;  // 64*1088*64 floats = 17.8 MB

  cost_kernel<<<NB * 24, 256, 0, stream>>>(x1, x2, diag);
  dtw_dp_kernel<<<NB, 64, 0, stream>>>(diag, out);
}